// Round 9
// baseline (506.814 us; speedup 1.0000x reference)
//
#include <hip/hip_runtime.h>
#include <math.h>

// Problem dims (fixed by the reference)
#define S_DIM 4096
#define H_DIM 4096
#define HC_N 4
#define HD_DIM 16384   // HC_N * H_DIM
#define MIXN 24        // (2+HC)*HC
#define SINK_IT 20

typedef float f32x4 __attribute__((ext_vector_type(4)));
typedef __bf16 bf16x8 __attribute__((ext_vector_type(8)));
typedef unsigned short u16x8 __attribute__((ext_vector_type(8)));
typedef unsigned short u16x4 __attribute__((ext_vector_type(4)));

__device__ __forceinline__ unsigned short f2bf(float f) {
  unsigned u = __builtin_bit_cast(unsigned, f);
  u += 0x7FFFu + ((u >> 16) & 1u);   // round-to-nearest-even
  return (unsigned short)(u >> 16);
}
__device__ __forceinline__ float bf2f(unsigned short h) {
  return __builtin_bit_cast(float, (unsigned)h << 16);
}

// ---------------------------------------------------------------------------
// K0: w_inner fp32 -> bf16
__global__ __launch_bounds__(256) void k_w2bf(const float* __restrict__ w,
                                              unsigned short* __restrict__ wb) {
  const size_t i = (size_t)(blockIdx.x * 256 + threadIdx.x) * 8;
  f32x4 a = *(const f32x4*)(w + i);
  f32x4 b = *(const f32x4*)(w + i + 4);
  u16x8 o;
  o[0] = f2bf(a.x); o[1] = f2bf(a.y); o[2] = f2bf(a.z); o[3] = f2bf(a.w);
  o[4] = f2bf(b.x); o[5] = f2bf(b.y); o[6] = f2bf(b.z); o[7] = f2bf(b.w);
  *(u16x8*)(wb + i) = o;
}

// ---------------------------------------------------------------------------
// K1: per-row mixes + sumsq + fused sigmoid/Sinkhorn gates.
// BARRIER-FREE: each wave owns 6 m's for the block's 4 rows and reads both
// hs (all 4 rows) and its fn rows DIRECTLY from global, 1-iter register
// prefetch. No LDS staging, no per-chunk __syncthreads -> no phase lockstep
// (the old staged version's HBM/L2/VALU terms serialized: ~119us vs ~55
// overlapped floor; co-resident blocks self-synchronized into bursts).
// hs re-read x4 is served by L1/L2 (4KB/row chunks, broadcast across waves).
// Gate math (sigmoid + 20-iter Sinkhorn) fused in the tail on 4 threads,
// hidden under other blocks' streaming; kills k_gates launch + round-trip.
__global__ __launch_bounds__(256) void k_mixes(const float* __restrict__ hs,
                                               const float* __restrict__ fn,
                                               const float* __restrict__ hbase,
                                               const float* __restrict__ hscale,
                                               float* __restrict__ gates) {
  __shared__ float smix[HC_N][MIXN];
  __shared__ float sss[HC_N];
  const int tid = threadIdx.x, lane = tid & 63, wave = tid >> 6;
  const int mb = wave * 6;
  const size_t rowbase = (size_t)blockIdx.x * HC_N * HD_DIM;
  const float* fb = fn + (size_t)mb * HD_DIM;

  float acc[HC_N][6];
#pragma unroll
  for (int r = 0; r < HC_N; r++)
#pragma unroll
    for (int j = 0; j < 6; j++) acc[r][j] = 0.f;
  float ss[HC_N] = {0.f, 0.f, 0.f, 0.f};

  // register prefetch of iter 0
  f32x4 ph[HC_N], pf[6];
  {
    const int d0 = lane * 4;
#pragma unroll
    for (int r = 0; r < HC_N; r++)
      ph[r] = *(const f32x4*)(hs + rowbase + (size_t)r * HD_DIM + d0);
#pragma unroll
    for (int j = 0; j < 6; j++)
      pf[j] = *(const f32x4*)(fb + (size_t)j * HD_DIM + d0);
  }

  for (int it = 0; it < 64; ++it) {
    f32x4 h4[HC_N], fv[6];
#pragma unroll
    for (int r = 0; r < HC_N; r++) h4[r] = ph[r];
#pragma unroll
    for (int j = 0; j < 6; j++) fv[j] = pf[j];
    if (it + 1 < 64) {
      const int dn = ((it + 1) * 64 + lane) * 4;
#pragma unroll
      for (int r = 0; r < HC_N; r++)
        ph[r] = *(const f32x4*)(hs + rowbase + (size_t)r * HD_DIM + dn);
#pragma unroll
      for (int j = 0; j < 6; j++)
        pf[j] = *(const f32x4*)(fb + (size_t)j * HD_DIM + dn);
    }
    if (wave == 0) {
#pragma unroll
      for (int r = 0; r < HC_N; r++)
        ss[r] += h4[r].x * h4[r].x + h4[r].y * h4[r].y + h4[r].z * h4[r].z + h4[r].w * h4[r].w;
    }
#pragma unroll
    for (int j = 0; j < 6; j++)
#pragma unroll
      for (int r = 0; r < HC_N; r++)
        acc[r][j] += h4[r].x * fv[j].x + h4[r].y * fv[j].y + h4[r].z * fv[j].z + h4[r].w * fv[j].w;
  }

  // per-wave shuffle reduction into LDS (wave owns its 6 m outright)
#pragma unroll
  for (int r = 0; r < HC_N; r++)
#pragma unroll
    for (int j = 0; j < 6; j++) {
      float v = acc[r][j];
#pragma unroll
      for (int off = 32; off >= 1; off >>= 1) v += __shfl_xor(v, off, 64);
      if (lane == 0) smix[r][mb + j] = v;
    }
  if (wave == 0) {
#pragma unroll
    for (int r = 0; r < HC_N; r++) {
      float v = ss[r];
#pragma unroll
      for (int off = 32; off >= 1; off >>= 1) v += __shfl_xor(v, off, 64);
      if (lane == 0) sss[r] = v;
    }
  }
  __syncthreads();

  // fused gates: sigmoid + 20-iter Sinkhorn, one thread per row
  if (tid < HC_N) {
    const int r = tid;
    const float rs = rsqrtf(sss[r] * (1.0f / HD_DIM) + 1e-6f);
    const float ps = hscale[0], qs = hscale[1], cs = hscale[2];
    float g[MIXN];
#pragma unroll
    for (int m = 0; m < MIXN; m++) {
      const float sc = (m < 4) ? ps : ((m < 8) ? qs : cs);
      const float x = smix[r][m] * rs * sc + hbase[m];
      g[m] = 1.0f / (1.0f + expf(-x)) + 1e-6f;
    }
    for (int t = 0; t < SINK_IT; t++) {
#pragma unroll
      for (int i = 0; i < 4; i++) {
        const float s = g[8 + i * 4 + 0] + g[8 + i * 4 + 1] + g[8 + i * 4 + 2] + g[8 + i * 4 + 3] + 1e-6f;
#pragma unroll
        for (int j = 0; j < 4; j++) g[8 + i * 4 + j] /= s;
      }
#pragma unroll
      for (int j = 0; j < 4; j++) {
        const float s = g[8 + 0 + j] + g[8 + 4 + j] + g[8 + 8 + j] + g[8 + 12 + j] + 1e-6f;
#pragma unroll
        for (int i = 0; i < 4; i++) g[8 + i * 4 + j] /= s;
      }
    }
    float* go = gates + (size_t)(blockIdx.x * HC_N + r) * MIXN;
#pragma unroll
    for (int m = 0; m < MIXN; m++) go[m] = g[m];
  }
}

// ---------------------------------------------------------------------------
// K3: reduced = pre . hs  -> RMSNorm -> normed (bf16).  One block per row s.
__global__ __launch_bounds__(256) void k_reduce_norm(const float* __restrict__ hs,
                                                     const float* __restrict__ gates,
                                                     const float* __restrict__ nw,
                                                     unsigned short* __restrict__ normed) {
  const int s = blockIdx.x, tid = threadIdx.x;
  const int lane = tid & 63, wave = tid >> 6;
  const float* g = gates + (size_t)s * MIXN;
  const float p0 = g[0], p1 = g[1], p2 = g[2], p3 = g[3];
  const size_t base = (size_t)s * HC_N * H_DIM;

  f32x4 red[4];
  float ssq = 0.f;
#pragma unroll
  for (int it = 0; it < 4; ++it) {
    const int d4 = it * 256 + tid;
    f32x4 a = *(const f32x4*)(hs + base + (size_t)0 * H_DIM + (size_t)d4 * 4);
    f32x4 b = *(const f32x4*)(hs + base + (size_t)1 * H_DIM + (size_t)d4 * 4);
    f32x4 c = *(const f32x4*)(hs + base + (size_t)2 * H_DIM + (size_t)d4 * 4);
    f32x4 d = *(const f32x4*)(hs + base + (size_t)3 * H_DIM + (size_t)d4 * 4);
    f32x4 v = p0 * a + p1 * b + p2 * c + p3 * d;
    red[it] = v;
    ssq += v.x * v.x + v.y * v.y + v.z * v.z + v.w * v.w;
  }
#pragma unroll
  for (int off = 32; off >= 1; off >>= 1) ssq += __shfl_xor(ssq, off, 64);
  __shared__ float ls[4];
  if (lane == 0) ls[wave] = ssq;
  __syncthreads();
  const float tot = ls[0] + ls[1] + ls[2] + ls[3];
  const float nr = rsqrtf(tot * (1.0f / H_DIM) + 1e-6f);
#pragma unroll
  for (int it = 0; it < 4; ++it) {
    const int d4 = it * 256 + tid;
    f32x4 w = *(const f32x4*)(nw + (size_t)d4 * 4);
    f32x4 v = red[it] * nr;
    v = v * w;
    u16x4 o;
    o[0] = f2bf(v.x); o[1] = f2bf(v.y); o[2] = f2bf(v.z); o[3] = f2bf(v.w);
    *(u16x4*)(normed + (size_t)s * H_DIM + (size_t)d4 * 4) = o;
  }
}

// ---------------------------------------------------------------------------
// K4: bf16 GEMM  C[s][e] = sum_d A[s][d] * B[e][d]
// FROZEN (pre-committed R7 read): 256x256 8-phase schedule, rule-#18 fences,
// bijective quad swizzle chunk^((row>>1)&3). Conflicts 1.258e7 -> 0, dur
// null (192us, MfmaUtil 29%) => issue/barrier-bound at 1 block/CU; five
// structural variants in the 192-209us band.
__device__ __forceinline__ void gload_lds16(const unsigned short* g, unsigned short* l) {
  __builtin_amdgcn_global_load_lds(
      (const __attribute__((address_space(1))) unsigned int*)(const void*)g,
      (__attribute__((address_space(3))) unsigned int*)(void*)l, 16, 0, 0);
}

#define VMW(n) asm volatile("s_waitcnt vmcnt(" #n ")" ::: "memory")
#define BAR    asm volatile("s_barrier" ::: "memory")
#define LGK0   asm volatile("s_waitcnt lgkmcnt(0)" ::: "memory")
#define SCB    __builtin_amdgcn_sched_barrier(0)

__global__ __launch_bounds__(512, 2) void k_gemm(const unsigned short* __restrict__ A,
                                                 const unsigned short* __restrict__ B,
                                                 unsigned short* __restrict__ C) {
  __shared__ __align__(16) unsigned short sAbuf[2][2][256 * 32];
  __shared__ __align__(16) unsigned short sBbuf[2][2][256 * 32];
  const int tid = threadIdx.x;
  const int lane = tid & 63, wave = tid >> 6;

  // Bijective XCD swizzle (256 blocks % 8 == 0): XCD v owns bn in {2v,2v+1}.
  const int bid = blockIdx.x;
  const int v = bid & 7, u = bid >> 3;          // u in 0..31
  const int bm = u & 15, bn = v * 2 + (u >> 4);
  const int wm = wave >> 2, wn = wave & 3;      // 2x4 wave grid, 128x64 per wave

  // staging: wave stages rows [wave*32, +32) of a [256][32] k-half, 2 instr.
  // Pre-swizzled global source: logical chunk = (lane&3) ^ ((row>>1)&3),
  // row = lane>>2 (row>>1 bits == lane>>3; +16/+32 offsets are %4-invariant).
  const int srow = lane >> 2;                              // 0..15
  const int sk8 = (((lane & 3) ^ ((lane >> 3) & 3)) * 8);  // swizzled k-offset
  const unsigned short* gA = A + (size_t)(bm * 256 + wave * 32 + srow) * 4096 + sk8;
  const unsigned short* gB = B + (size_t)(bn * 256 + wave * 32 + srow) * 4096 + sk8;
  const int ld0 = wave * 1024 + lane * 8;   // element offset, instr 0 (linear dest)
  const int ld1 = ld0 + 512;                // rows +16..31

  f32x4 acc[8][4];
  f32x4 zero = {0.f, 0.f, 0.f, 0.f};
#pragma unroll
  for (int mf = 0; mf < 8; mf++)
#pragma unroll
    for (int nf = 0; nf < 4; nf++) acc[mf][nf] = zero;
  bf16x8 af[8];

  // fragment read: row = base16 + (lane&15); phys chunk = (lane>>4) ^ ((row>>1)&3)
  const int frow = lane & 15;
  const int fk = (((lane >> 4) ^ ((lane >> 1) & 3)) * 8);   // swizzled read offset

#define PHASE_BODY(db, kh, nh, dostg, sdst, gsrc, t, skh) do {                  \
    if ((nh) == 0) {                                                            \
      _Pragma("unroll") for (int mf = 0; mf < 8; mf++)                          \
        af[mf] = *(const bf16x8*)&sAbuf[db][kh][(wm * 128 + mf * 16 + frow) * 32 + fk]; \
    }                                                                           \
    bf16x8 b0 = *(const bf16x8*)&sBbuf[db][kh][(wn * 64 + ((nh) * 2 + 0) * 16 + frow) * 32 + fk]; \
    bf16x8 b1 = *(const bf16x8*)&sBbuf[db][kh][(wn * 64 + ((nh) * 2 + 1) * 16 + frow) * 32 + fk]; \
    if (dostg) {                                                                \
      const unsigned short* _g = (gsrc) + (size_t)(t) * 64 + (skh) * 32;        \
      gload_lds16(_g,              (sdst) + ld0);                               \
      gload_lds16(_g + 16 * 4096,  (sdst) + ld1);                               \
    }                                                                           \
    SCB;                                                                        \
    BAR;                                                                        \
    LGK0;                                                                       \
    SCB;                                                                        \
    __builtin_amdgcn_s_setprio(1);                                              \
    _Pragma("unroll") for (int mf = 0; mf < 8; mf++) {                          \
      acc[mf][(nh) * 2 + 0] = __builtin_amdgcn_mfma_f32_16x16x32_bf16(af[mf], b0, acc[mf][(nh) * 2 + 0], 0, 0, 0); \
      acc[mf][(nh) * 2 + 1] = __builtin_amdgcn_mfma_f32_16x16x32_bf16(af[mf], b1, acc[mf][(nh) * 2 + 1], 0, 0, 0); \
    }                                                                           \
    __builtin_amdgcn_s_setprio(0);                                              \
    SCB;                                                                        \
  } while (0)

  // prologue: tile 0 -> db0 in order A-kh0, B-kh0, A-kh1, B-kh1
  gload_lds16(gA,                  &sAbuf[0][0][0] + ld0);
  gload_lds16(gA + 16 * 4096,      &sAbuf[0][0][0] + ld1);
  gload_lds16(gB,                  &sBbuf[0][0][0] + ld0);
  gload_lds16(gB + 16 * 4096,      &sBbuf[0][0][0] + ld1);
  gload_lds16(gA + 32,             &sAbuf[0][1][0] + ld0);
  gload_lds16(gA + 32 + 16 * 4096, &sAbuf[0][1][0] + ld1);
  gload_lds16(gB + 32,             &sBbuf[0][1][0] + ld0);
  gload_lds16(gB + 32 + 16 * 4096, &sBbuf[0][1][0] + ld1);
  VMW(4);   // A-kh0, B-kh0 of tile 0 arrived
  BAR;

  for (int i = 0; i < 31; ++i) {
    const int t1 = 2 * i + 1, t2 = 2 * i + 2;
    PHASE_BODY(0, 0, 0, 1, &sAbuf[1][0][0], gA, t1, 0);          BAR;
    PHASE_BODY(0, 0, 1, 1, &sBbuf[1][0][0], gB, t1, 0); VMW(4);  BAR;
    PHASE_BODY(0, 1, 0, 1, &sAbuf[1][1][0], gA, t1, 1);          BAR;
    PHASE_BODY(0, 1, 1, 1, &sBbuf[1][1][0], gB, t1, 1); VMW(4);  BAR;
    PHASE_BODY(1, 0, 0, 1, &sAbuf[0][0][0], gA, t2, 0);          BAR;
    PHASE_BODY(1, 0, 1, 1, &sBbuf[0][0][0], gB, t2, 0); VMW(4);  BAR;
    PHASE_BODY(1, 1, 0, 1, &sAbuf[0][1][0], gA, t2, 1);          BAR;
    PHASE_BODY(1, 1, 1, 1, &sBbuf[0][1][0], gB, t2, 1); VMW(4);  BAR;
  }
  // peeled last iteration (i = 31): stage tile 63 only; drain with vmcnt(0)
  PHASE_BODY(0, 0, 0, 1, &sAbuf[1][0][0], gA, 63, 0);            BAR;
  PHASE_BODY(0, 0, 1, 1, &sBbuf[1][0][0], gB, 63, 0); VMW(4);    BAR;
  PHASE_BODY(0, 1, 0, 1, &sAbuf[1][1][0], gA, 63, 1);            BAR;
  PHASE_BODY(0, 1, 1, 1, &sBbuf[1][1][0], gB, 63, 1); VMW(0);    BAR;
  PHASE_BODY(1, 0, 0, 0, &sAbuf[0][0][0], gA, 0, 0);             BAR;
  PHASE_BODY(1, 0, 1, 0, &sAbuf[0][0][0], gA, 0, 0);             BAR;
  PHASE_BODY(1, 1, 0, 0, &sAbuf[0][0][0], gA, 0, 0);             BAR;
  PHASE_BODY(1, 1, 1, 0, &sAbuf[0][0][0], gA, 0, 0);

#undef PHASE_BODY

  // epilogue: C write (bf16)
  const int crow0 = bm * 256 + wm * 128 + (lane >> 4) * 4;
  const int ccol0 = bn * 256 + wn * 64 + (lane & 15);
#pragma unroll
  for (int mf = 0; mf < 8; mf++)
#pragma unroll
    for (int nf = 0; nf < 4; nf++)
#pragma unroll
      for (int j = 0; j < 4; j++)
        C[(size_t)(crow0 + mf * 16 + j) * 4096 + ccol0 + nf * 16] = f2bf(acc[mf][nf][j]);
}

// ---------------------------------------------------------------------------
// K5: expanded[s][h][d] = post[h]*out[s][d] + sum_k comb[h][k]*hs[s][k][d]
__global__ __launch_bounds__(256) void k_expand(const float* __restrict__ hs,
                                                const unsigned short* __restrict__ outb,
                                                const float* __restrict__ gates,
                                                float* __restrict__ y) {
  const int s = blockIdx.x, tid = threadIdx.x;
  const float* g = gates + (size_t)s * MIXN;
  float post[4], cb[4][4];
#pragma unroll
  for (int h = 0; h < 4; h++) post[h] = g[4 + h];
#pragma unroll
  for (int h = 0; h < 4; h++)
#pragma unroll
    for (int k = 0; k < 4; k++) cb[h][k] = g[8 + h * 4 + k];

  const size_t base = (size_t)s * HC_N * H_DIM;
#pragma unroll
  for (int it = 0; it < 4; ++it) {
    const int d4 = it * 256 + tid;
    f32x4 hv[4];
#pragma unroll
    for (int k = 0; k < 4; k++)
      hv[k] = *(const f32x4*)(hs + base + (size_t)k * H_DIM + (size_t)d4 * 4);
    u16x4 ob = *(const u16x4*)(outb + (size_t)s * H_DIM + (size_t)d4 * 4);
    f32x4 o = {bf2f(ob[0]), bf2f(ob[1]), bf2f(ob[2]), bf2f(ob[3])};
#pragma unroll
    for (int h = 0; h < 4; h++) {
      f32x4 e = post[h] * o + cb[h][0] * hv[0] + cb[h][1] * hv[1] + cb[h][2] * hv[2] + cb[h][3] * hv[3];
      *(f32x4*)(y + base + (size_t)h * H_DIM + (size_t)d4 * 4) = e;
    }
  }
}

// ---------------------------------------------------------------------------
extern "C" void kernel_launch(void* const* d_in, const int* in_sizes, int n_in,
                              void* d_out, int out_size, void* d_ws, size_t ws_size,
                              hipStream_t stream) {
  const float* hs = (const float*)d_in[0];      // [1,4096,4,4096]
  const float* fn = (const float*)d_in[1];      // [24,16384]
  const float* hbase = (const float*)d_in[2];   // [24]
  const float* hscale = (const float*)d_in[3];  // [3]
  const float* nw = (const float*)d_in[4];      // [4096]
  const float* wi = (const float*)d_in[5];      // [4096,4096]
  float* y = (float*)d_out;                     // [1,4096,4,4096] fp32

  char* ws = (char*)d_ws;
  float* gates = (float*)(ws + 409600);                                // 393216 B
  unsigned short* normed = (unsigned short*)(ws + 1048576);            // 32MB bf16
  unsigned short* wb = (unsigned short*)(ws + 1048576 + 33554432);     // 32MB bf16
  unsigned short* outb = (unsigned short*)(ws + 1048576 + 2 * 33554432); // 32MB bf16
  // total ws use: ~97MB

  k_w2bf<<<8192, 256, 0, stream>>>(wi, wb);
  k_mixes<<<1024, 256, 0, stream>>>(hs, fn, hbase, hscale, gates);
  k_reduce_norm<<<4096, 256, 0, stream>>>(hs, gates, nw, normed);
  k_gemm<<<256, 512, 0, stream>>>(normed, wb, outb);
  k_expand<<<4096, 256, 0, stream>>>(hs, outb, gates, y);
}

// Round 10
// 476.570 us; speedup vs baseline: 1.0635x; 1.0635x over previous
//
#include <hip/hip_runtime.h>
#include <math.h>

// Problem dims (fixed by the reference)
#define S_DIM 4096
#define H_DIM 4096
#define HC_N 4
#define HD_DIM 16384   // HC_N * H_DIM
#define MIXN 24        // (2+HC)*HC
#define SINK_IT 20

typedef float f32x4 __attribute__((ext_vector_type(4)));
typedef __bf16 bf16x8 __attribute__((ext_vector_type(8)));
typedef unsigned short u16x8 __attribute__((ext_vector_type(8)));
typedef unsigned short u16x4 __attribute__((ext_vector_type(4)));

__device__ __forceinline__ unsigned short f2bf(float f) {
  unsigned u = __builtin_bit_cast(unsigned, f);
  u += 0x7FFFu + ((u >> 16) & 1u);   // round-to-nearest-even
  return (unsigned short)(u >> 16);
}
__device__ __forceinline__ float bf2f(unsigned short h) {
  return __builtin_bit_cast(float, (unsigned)h << 16);
}

// ---------------------------------------------------------------------------
// K0: w_inner fp32 -> bf16
__global__ __launch_bounds__(256) void k_w2bf(const float* __restrict__ w,
                                              unsigned short* __restrict__ wb) {
  const size_t i = (size_t)(blockIdx.x * 256 + threadIdx.x) * 8;
  f32x4 a = *(const f32x4*)(w + i);
  f32x4 b = *(const f32x4*)(w + i + 4);
  u16x8 o;
  o[0] = f2bf(a.x); o[1] = f2bf(a.y); o[2] = f2bf(a.z); o[3] = f2bf(a.w);
  o[4] = f2bf(b.x); o[5] = f2bf(b.y); o[6] = f2bf(b.z); o[7] = f2bf(b.w);
  *(u16x8*)(wb + i) = o;
}

// ---------------------------------------------------------------------------
// K1: per-row mixes_raw[s][24] = flat[s,:] . hc_fn[m,:]  and sumsq[s]
// R2 proven structure (4 rows/block, m-split across waves) + round-9 ILP
// upgrades targeting the exposed L2 latency (kernel was latency-bound at
// ~1 TB/s effective, VALUBusy 17%):
//  (a) double-buffered LDS [2][4][1024] (32KB): ONE barrier per chunk; next
//      hs chunk's global loads issue at iteration top and drain across the
//      whole compute phase.
//  (b) fn register prefetch: ii+1's 6 fn vectors load during ii's 96 FMAs
//      (~192 cyc covers ~200 cyc L2 latency).
// VGPR ~110 stays in the <=128 tier -> occupancy unchanged.
__global__ __launch_bounds__(256) void k_mixes(const float* __restrict__ hs,
                                               const float* __restrict__ fn,
                                               float* __restrict__ mixraw,
                                               float* __restrict__ sumsq) {
  __shared__ __align__(16) float lds[2][HC_N][1024];
  const int tid = threadIdx.x;
  const int b = blockIdx.x;          // rows 4b..4b+3
  const int lane = tid & 63, wave = tid >> 6;
  const int mbase = wave * 6;

  float acc[HC_N][6];
  float ss[HC_N];
#pragma unroll
  for (int r = 0; r < HC_N; r++) {
    ss[r] = 0.f;
#pragma unroll
    for (int j = 0; j < 6; j++) acc[r][j] = 0.f;
  }

  const size_t rowbase = (size_t)b * HC_N * HD_DIM;

  // prologue: stage chunk 0 into buffer 0
#pragma unroll
  for (int r = 0; r < HC_N; r++) {
    f32x4 v = *(const f32x4*)(hs + rowbase + (size_t)r * HD_DIM + tid * 4);
    *(f32x4*)(&lds[0][r][tid * 4]) = v;
  }
  __syncthreads();

  for (int it = 0; it < 16; ++it) {
    const int cur = it & 1;
    // issue next chunk's global loads early (drain across compute phase)
    f32x4 nx[HC_N];
    if (it + 1 < 16) {
#pragma unroll
      for (int r = 0; r < HC_N; r++)
        nx[r] = *(const f32x4*)(hs + rowbase + (size_t)r * HD_DIM + (it + 1) * 1024 + tid * 4);
    }
    // fn prefetch for ii = 0
    f32x4 fvp[6];
#pragma unroll
    for (int j = 0; j < 6; j++)
      fvp[j] = *(const f32x4*)(fn + (size_t)(mbase + j) * HD_DIM + it * 1024 + lane * 4);

#pragma unroll
    for (int ii = 0; ii < 4; ii++) {
      const int c4 = ii * 64 + lane;   // f32x4 index within the 1024-float chunk
      f32x4 h4[HC_N];
#pragma unroll
      for (int r = 0; r < HC_N; r++) h4[r] = *(const f32x4*)(&lds[cur][r][c4 * 4]);
      f32x4 fv[6];
#pragma unroll
      for (int j = 0; j < 6; j++) fv[j] = fvp[j];
      if (ii + 1 < 4) {
#pragma unroll
        for (int j = 0; j < 6; j++)
          fvp[j] = *(const f32x4*)(fn + (size_t)(mbase + j) * HD_DIM + it * 1024 + (c4 + 64) * 4);
      }
      if (wave == 0) {
#pragma unroll
        for (int r = 0; r < HC_N; r++)
          ss[r] += h4[r].x * h4[r].x + h4[r].y * h4[r].y + h4[r].z * h4[r].z + h4[r].w * h4[r].w;
      }
#pragma unroll
      for (int j = 0; j < 6; j++) {
#pragma unroll
        for (int r = 0; r < HC_N; r++)
          acc[r][j] += h4[r].x * fv[j].x + h4[r].y * fv[j].y + h4[r].z * fv[j].z + h4[r].w * fv[j].w;
      }
    }

    // write next chunk into the other buffer (its readers finished at the
    // PREVIOUS barrier), then one barrier makes it visible for it+1
    if (it + 1 < 16) {
#pragma unroll
      for (int r = 0; r < HC_N; r++)
        *(f32x4*)(&lds[cur ^ 1][r][tid * 4]) = nx[r];
      __syncthreads();
    }
  }

  // per-wave shuffle reduction; each wave owns its 6 m values outright
#pragma unroll
  for (int r = 0; r < HC_N; r++) {
#pragma unroll
    for (int j = 0; j < 6; j++) {
      float v = acc[r][j];
#pragma unroll
      for (int off = 32; off >= 1; off >>= 1) v += __shfl_xor(v, off, 64);
      if (lane == 0) mixraw[(size_t)(b * 4 + r) * MIXN + mbase + j] = v;
    }
  }
  if (wave == 0) {
#pragma unroll
    for (int r = 0; r < HC_N; r++) {
      float v = ss[r];
#pragma unroll
      for (int off = 32; off >= 1; off >>= 1) v += __shfl_xor(v, off, 64);
      if (lane == 0) sumsq[b * 4 + r] = v;
    }
  }
}

// ---------------------------------------------------------------------------
// K2: gates = {pre[4], post[4], sinkhorn(comb)[16]} per row
__global__ __launch_bounds__(256) void k_gates(const float* __restrict__ mixraw,
                                               const float* __restrict__ sumsq,
                                               const float* __restrict__ hbase,
                                               const float* __restrict__ hscale,
                                               float* __restrict__ gates) {
  const int row = blockIdx.x * 256 + threadIdx.x;
  const float rs = rsqrtf(sumsq[row] * (1.0f / HD_DIM) + 1e-6f);
  const float ps = hscale[0], qs = hscale[1], cs = hscale[2];
  const float* mr = mixraw + (size_t)row * MIXN;
  float g[MIXN];
#pragma unroll
  for (int m = 0; m < MIXN; m++) {
    const float sc = (m < 4) ? ps : ((m < 8) ? qs : cs);
    const float x = mr[m] * rs * sc + hbase[m];
    g[m] = 1.0f / (1.0f + expf(-x)) + 1e-6f;
  }
  // 20-iter Sinkhorn on g[8..23] viewed as c[i][j] = g[8+i*4+j]
  for (int t = 0; t < SINK_IT; t++) {
#pragma unroll
    for (int i = 0; i < 4; i++) {
      const float s = g[8 + i * 4 + 0] + g[8 + i * 4 + 1] + g[8 + i * 4 + 2] + g[8 + i * 4 + 3] + 1e-6f;
#pragma unroll
      for (int j = 0; j < 4; j++) g[8 + i * 4 + j] /= s;
    }
#pragma unroll
    for (int j = 0; j < 4; j++) {
      const float s = g[8 + 0 + j] + g[8 + 4 + j] + g[8 + 8 + j] + g[8 + 12 + j] + 1e-6f;
#pragma unroll
      for (int i = 0; i < 4; i++) g[8 + i * 4 + j] /= s;
    }
  }
  float* go = gates + (size_t)row * MIXN;
#pragma unroll
  for (int m = 0; m < MIXN; m++) go[m] = g[m];
}

// ---------------------------------------------------------------------------
// K3: reduced = pre . hs  -> RMSNorm -> normed (bf16).  One block per row s.
__global__ __launch_bounds__(256) void k_reduce_norm(const float* __restrict__ hs,
                                                     const float* __restrict__ gates,
                                                     const float* __restrict__ nw,
                                                     unsigned short* __restrict__ normed) {
  const int s = blockIdx.x, tid = threadIdx.x;
  const int lane = tid & 63, wave = tid >> 6;
  const float* g = gates + (size_t)s * MIXN;
  const float p0 = g[0], p1 = g[1], p2 = g[2], p3 = g[3];
  const size_t base = (size_t)s * HC_N * H_DIM;

  f32x4 red[4];
  float ssq = 0.f;
#pragma unroll
  for (int it = 0; it < 4; ++it) {
    const int d4 = it * 256 + tid;
    f32x4 a = *(const f32x4*)(hs + base + (size_t)0 * H_DIM + (size_t)d4 * 4);
    f32x4 b = *(const f32x4*)(hs + base + (size_t)1 * H_DIM + (size_t)d4 * 4);
    f32x4 c = *(const f32x4*)(hs + base + (size_t)2 * H_DIM + (size_t)d4 * 4);
    f32x4 d = *(const f32x4*)(hs + base + (size_t)3 * H_DIM + (size_t)d4 * 4);
    f32x4 v = p0 * a + p1 * b + p2 * c + p3 * d;
    red[it] = v;
    ssq += v.x * v.x + v.y * v.y + v.z * v.z + v.w * v.w;
  }
#pragma unroll
  for (int off = 32; off >= 1; off >>= 1) ssq += __shfl_xor(ssq, off, 64);
  __shared__ float ls[4];
  if (lane == 0) ls[wave] = ssq;
  __syncthreads();
  const float tot = ls[0] + ls[1] + ls[2] + ls[3];
  const float nr = rsqrtf(tot * (1.0f / H_DIM) + 1e-6f);
#pragma unroll
  for (int it = 0; it < 4; ++it) {
    const int d4 = it * 256 + tid;
    f32x4 w = *(const f32x4*)(nw + (size_t)d4 * 4);
    f32x4 v = red[it] * nr;
    v = v * w;
    u16x4 o;
    o[0] = f2bf(v.x); o[1] = f2bf(v.y); o[2] = f2bf(v.z); o[3] = f2bf(v.w);
    *(u16x4*)(normed + (size_t)s * H_DIM + (size_t)d4 * 4) = o;
  }
}

// ---------------------------------------------------------------------------
// K4: bf16 GEMM  C[s][e] = sum_d A[s][d] * B[e][d]
// FROZEN (pre-committed R7 read): 256x256 8-phase schedule, rule-#18 fences,
// bijective quad swizzle chunk^((row>>1)&3). Conflicts 1.258e7 -> 0, dur
// null (192us, MfmaUtil 29%) => issue/barrier-bound at 1 block/CU; five
// structural variants in the 192-209us band.
__device__ __forceinline__ void gload_lds16(const unsigned short* g, unsigned short* l) {
  __builtin_amdgcn_global_load_lds(
      (const __attribute__((address_space(1))) unsigned int*)(const void*)g,
      (__attribute__((address_space(3))) unsigned int*)(void*)l, 16, 0, 0);
}

#define VMW(n) asm volatile("s_waitcnt vmcnt(" #n ")" ::: "memory")
#define BAR    asm volatile("s_barrier" ::: "memory")
#define LGK0   asm volatile("s_waitcnt lgkmcnt(0)" ::: "memory")
#define SCB    __builtin_amdgcn_sched_barrier(0)

__global__ __launch_bounds__(512, 2) void k_gemm(const unsigned short* __restrict__ A,
                                                 const unsigned short* __restrict__ B,
                                                 unsigned short* __restrict__ C) {
  __shared__ __align__(16) unsigned short sAbuf[2][2][256 * 32];
  __shared__ __align__(16) unsigned short sBbuf[2][2][256 * 32];
  const int tid = threadIdx.x;
  const int lane = tid & 63, wave = tid >> 6;

  // Bijective XCD swizzle (256 blocks % 8 == 0): XCD v owns bn in {2v,2v+1}.
  const int bid = blockIdx.x;
  const int v = bid & 7, u = bid >> 3;          // u in 0..31
  const int bm = u & 15, bn = v * 2 + (u >> 4);
  const int wm = wave >> 2, wn = wave & 3;      // 2x4 wave grid, 128x64 per wave

  // staging: wave stages rows [wave*32, +32) of a [256][32] k-half, 2 instr.
  // Pre-swizzled global source: logical chunk = (lane&3) ^ ((row>>1)&3),
  // row = lane>>2 (row>>1 bits == lane>>3; +16/+32 offsets are %4-invariant).
  const int srow = lane >> 2;                              // 0..15
  const int sk8 = (((lane & 3) ^ ((lane >> 3) & 3)) * 8);  // swizzled k-offset
  const unsigned short* gA = A + (size_t)(bm * 256 + wave * 32 + srow) * 4096 + sk8;
  const unsigned short* gB = B + (size_t)(bn * 256 + wave * 32 + srow) * 4096 + sk8;
  const int ld0 = wave * 1024 + lane * 8;   // element offset, instr 0 (linear dest)
  const int ld1 = ld0 + 512;                // rows +16..31

  f32x4 acc[8][4];
  f32x4 zero = {0.f, 0.f, 0.f, 0.f};
#pragma unroll
  for (int mf = 0; mf < 8; mf++)
#pragma unroll
    for (int nf = 0; nf < 4; nf++) acc[mf][nf] = zero;
  bf16x8 af[8];

  // fragment read: row = base16 + (lane&15); phys chunk = (lane>>4) ^ ((row>>1)&3)
  const int frow = lane & 15;
  const int fk = (((lane >> 4) ^ ((lane >> 1) & 3)) * 8);   // swizzled read offset

#define PHASE_BODY(db, kh, nh, dostg, sdst, gsrc, t, skh) do {                  \
    if ((nh) == 0) {                                                            \
      _Pragma("unroll") for (int mf = 0; mf < 8; mf++)                          \
        af[mf] = *(const bf16x8*)&sAbuf[db][kh][(wm * 128 + mf * 16 + frow) * 32 + fk]; \
    }                                                                           \
    bf16x8 b0 = *(const bf16x8*)&sBbuf[db][kh][(wn * 64 + ((nh) * 2 + 0) * 16 + frow) * 32 + fk]; \
    bf16x8 b1 = *(const bf16x8*)&sBbuf[db][kh][(wn * 64 + ((nh) * 2 + 1) * 16 + frow) * 32 + fk]; \
    if (dostg) {                                                                \
      const unsigned short* _g = (gsrc) + (size_t)(t) * 64 + (skh) * 32;        \
      gload_lds16(_g,              (sdst) + ld0);                               \
      gload_lds16(_g + 16 * 4096,  (sdst) + ld1);                               \
    }                                                                           \
    SCB;                                                                        \
    BAR;                                                                        \
    LGK0;                                                                       \
    SCB;                                                                        \
    __builtin_amdgcn_s_setprio(1);                                              \
    _Pragma("unroll") for (int mf = 0; mf < 8; mf++) {                          \
      acc[mf][(nh) * 2 + 0] = __builtin_amdgcn_mfma_f32_16x16x32_bf16(af[mf], b0, acc[mf][(nh) * 2 + 0], 0, 0, 0); \
      acc[mf][(nh) * 2 + 1] = __builtin_amdgcn_mfma_f32_16x16x32_bf16(af[mf], b1, acc[mf][(nh) * 2 + 1], 0, 0, 0); \
    }                                                                           \
    __builtin_amdgcn_s_setprio(0);                                              \
    SCB;                                                                        \
  } while (0)

  // prologue: tile 0 -> db0 in order A-kh0, B-kh0, A-kh1, B-kh1
  gload_lds16(gA,                  &sAbuf[0][0][0] + ld0);
  gload_lds16(gA + 16 * 4096,      &sAbuf[0][0][0] + ld1);
  gload_lds16(gB,                  &sBbuf[0][0][0] + ld0);
  gload_lds16(gB + 16 * 4096,      &sBbuf[0][0][0] + ld1);
  gload_lds16(gA + 32,             &sAbuf[0][1][0] + ld0);
  gload_lds16(gA + 32 + 16 * 4096, &sAbuf[0][1][0] + ld1);
  gload_lds16(gB + 32,             &sBbuf[0][1][0] + ld0);
  gload_lds16(gB + 32 + 16 * 4096, &sBbuf[0][1][0] + ld1);
  VMW(4);   // A-kh0, B-kh0 of tile 0 arrived
  BAR;

  for (int i = 0; i < 31; ++i) {
    const int t1 = 2 * i + 1, t2 = 2 * i + 2;
    PHASE_BODY(0, 0, 0, 1, &sAbuf[1][0][0], gA, t1, 0);          BAR;
    PHASE_BODY(0, 0, 1, 1, &sBbuf[1][0][0], gB, t1, 0); VMW(4);  BAR;
    PHASE_BODY(0, 1, 0, 1, &sAbuf[1][1][0], gA, t1, 1);          BAR;
    PHASE_BODY(0, 1, 1, 1, &sBbuf[1][1][0], gB, t1, 1); VMW(4);  BAR;
    PHASE_BODY(1, 0, 0, 1, &sAbuf[0][0][0], gA, t2, 0);          BAR;
    PHASE_BODY(1, 0, 1, 1, &sBbuf[0][0][0], gB, t2, 0); VMW(4);  BAR;
    PHASE_BODY(1, 1, 0, 1, &sAbuf[0][1][0], gA, t2, 1);          BAR;
    PHASE_BODY(1, 1, 1, 1, &sBbuf[0][1][0], gB, t2, 1); VMW(4);  BAR;
  }
  // peeled last iteration (i = 31): stage tile 63 only; drain with vmcnt(0)
  PHASE_BODY(0, 0, 0, 1, &sAbuf[1][0][0], gA, 63, 0);            BAR;
  PHASE_BODY(0, 0, 1, 1, &sBbuf[1][0][0], gB, 63, 0); VMW(4);    BAR;
  PHASE_BODY(0, 1, 0, 1, &sAbuf[1][1][0], gA, 63, 1);            BAR;
  PHASE_BODY(0, 1, 1, 1, &sBbuf[1][1][0], gB, 63, 1); VMW(0);    BAR;
  PHASE_BODY(1, 0, 0, 0, &sAbuf[0][0][0], gA, 0, 0);             BAR;
  PHASE_BODY(1, 0, 1, 0, &sAbuf[0][0][0], gA, 0, 0);             BAR;
  PHASE_BODY(1, 1, 0, 0, &sAbuf[0][0][0], gA, 0, 0);             BAR;
  PHASE_BODY(1, 1, 1, 0, &sAbuf[0][0][0], gA, 0, 0);

#undef PHASE_BODY

  // epilogue: C write (bf16)
  const int crow0 = bm * 256 + wm * 128 + (lane >> 4) * 4;
  const int ccol0 = bn * 256 + wn * 64 + (lane & 15);
#pragma unroll
  for (int mf = 0; mf < 8; mf++)
#pragma unroll
    for (int nf = 0; nf < 4; nf++)
#pragma unroll
      for (int j = 0; j < 4; j++)
        C[(size_t)(crow0 + mf * 16 + j) * 4096 + ccol0 + nf * 16] = f2bf(acc[mf][nf][j]);
}

// ---------------------------------------------------------------------------
// K5: expanded[s][h][d] = post[h]*out[s][d] + sum_k comb[h][k]*hs[s][k][d]
__global__ __launch_bounds__(256) void k_expand(const float* __restrict__ hs,
                                                const unsigned short* __restrict__ outb,
                                                const float* __restrict__ gates,
                                                float* __restrict__ y) {
  const int s = blockIdx.x, tid = threadIdx.x;
  const float* g = gates + (size_t)s * MIXN;
  float post[4], cb[4][4];
#pragma unroll
  for (int h = 0; h < 4; h++) post[h] = g[4 + h];
#pragma unroll
  for (int h = 0; h < 4; h++)
#pragma unroll
    for (int k = 0; k < 4; k++) cb[h][k] = g[8 + h * 4 + k];

  const size_t base = (size_t)s * HC_N * H_DIM;
#pragma unroll
  for (int it = 0; it < 4; ++it) {
    const int d4 = it * 256 + tid;
    f32x4 hv[4];
#pragma unroll
    for (int k = 0; k < 4; k++)
      hv[k] = *(const f32x4*)(hs + base + (size_t)k * H_DIM + (size_t)d4 * 4);
    u16x4 ob = *(const u16x4*)(outb + (size_t)s * H_DIM + (size_t)d4 * 4);
    f32x4 o = {bf2f(ob[0]), bf2f(ob[1]), bf2f(ob[2]), bf2f(ob[3])};
#pragma unroll
    for (int h = 0; h < 4; h++) {
      f32x4 e = post[h] * o + cb[h][0] * hv[0] + cb[h][1] * hv[1] + cb[h][2] * hv[2] + cb[h][3] * hv[3];
      *(f32x4*)(y + base + (size_t)h * H_DIM + (size_t)d4 * 4) = e;
    }
  }
}

// ---------------------------------------------------------------------------
extern "C" void kernel_launch(void* const* d_in, const int* in_sizes, int n_in,
                              void* d_out, int out_size, void* d_ws, size_t ws_size,
                              hipStream_t stream) {
  const float* hs = (const float*)d_in[0];      // [1,4096,4,4096]
  const float* fn = (const float*)d_in[1];      // [24,16384]
  const float* hbase = (const float*)d_in[2];   // [24]
  const float* hscale = (const float*)d_in[3];  // [3]
  const float* nw = (const float*)d_in[4];      // [4096]
  const float* wi = (const float*)d_in[5];      // [4096,4096]
  float* y = (float*)d_out;                     // [1,4096,4,4096] fp32

  char* ws = (char*)d_ws;
  float* mixraw = (float*)(ws);                            // 4096*24*4   = 393216
  float* sumsq = (float*)(ws + 393216);                    // 4096*4      = 16384
  float* gates = (float*)(ws + 409600);                    // 4096*24*4   = 393216
  unsigned short* normed = (unsigned short*)(ws + 1048576);            // 32MB bf16
  unsigned short* wb = (unsigned short*)(ws + 1048576 + 33554432);     // 32MB bf16
  unsigned short* outb = (unsigned short*)(ws + 1048576 + 2 * 33554432); // 32MB bf16
  // total ws use: ~97MB

  k_w2bf<<<8192, 256, 0, stream>>>(wi, wb);
  k_mixes<<<1024, 256, 0, stream>>>(hs, fn, mixraw, sumsq);
  k_gates<<<16, 256, 0, stream>>>(mixraw, sumsq, hbase, hscale, gates);
  k_reduce_norm<<<4096, 256, 0, stream>>>(hs, gates, nw, normed);
  k_gemm<<<256, 512, 0, stream>>>(normed, wb, outb);
  k_expand<<<4096, 256, 0, stream>>>(hs, outb, gates, y);
}

// Round 11
// 457.703 us; speedup vs baseline: 1.1073x; 1.0412x over previous
//
#include <hip/hip_runtime.h>
#include <math.h>

// Problem dims (fixed by the reference)
#define S_DIM 4096
#define H_DIM 4096
#define HC_N 4
#define HD_DIM 16384   // HC_N * H_DIM
#define MIXN 24        // (2+HC)*HC
#define SINK_IT 20

typedef float f32x4 __attribute__((ext_vector_type(4)));
typedef __bf16 bf16x8 __attribute__((ext_vector_type(8)));
typedef unsigned short u16x8 __attribute__((ext_vector_type(8)));
typedef unsigned short u16x4 __attribute__((ext_vector_type(4)));

__device__ __forceinline__ unsigned short f2bf(float f) {
  unsigned u = __builtin_bit_cast(unsigned, f);
  u += 0x7FFFu + ((u >> 16) & 1u);   // round-to-nearest-even
  return (unsigned short)(u >> 16);
}
__device__ __forceinline__ float bf2f(unsigned short h) {
  return __builtin_bit_cast(float, (unsigned)h << 16);
}

// ---------------------------------------------------------------------------
// K0: w_inner fp32 -> bf16
__global__ __launch_bounds__(256) void k_w2bf(const float* __restrict__ w,
                                              unsigned short* __restrict__ wb) {
  const size_t i = (size_t)(blockIdx.x * 256 + threadIdx.x) * 8;
  f32x4 a = *(const f32x4*)(w + i);
  f32x4 b = *(const f32x4*)(w + i + 4);
  u16x8 o;
  o[0] = f2bf(a.x); o[1] = f2bf(a.y); o[2] = f2bf(a.z); o[3] = f2bf(a.w);
  o[4] = f2bf(b.x); o[5] = f2bf(b.y); o[6] = f2bf(b.z); o[7] = f2bf(b.w);
  *(u16x8*)(wb + i) = o;
}

// ---------------------------------------------------------------------------
// K1: per-row mixes_raw[s][24] = flat[s,:] . hc_fn[m,:]  and sumsq[s]
// R2 proven structure (4 rows/block, m-split across waves) + R10 ILP
// upgrades (double-buffered LDS, fn register prefetch). FROZEN: 6 attempts
// bracket this at 155-190us; this form is the best measured.
__global__ __launch_bounds__(256) void k_mixes(const float* __restrict__ hs,
                                               const float* __restrict__ fn,
                                               float* __restrict__ mixraw,
                                               float* __restrict__ sumsq) {
  __shared__ __align__(16) float lds[2][HC_N][1024];
  const int tid = threadIdx.x;
  const int b = blockIdx.x;          // rows 4b..4b+3
  const int lane = tid & 63, wave = tid >> 6;
  const int mbase = wave * 6;

  float acc[HC_N][6];
  float ss[HC_N];
#pragma unroll
  for (int r = 0; r < HC_N; r++) {
    ss[r] = 0.f;
#pragma unroll
    for (int j = 0; j < 6; j++) acc[r][j] = 0.f;
  }

  const size_t rowbase = (size_t)b * HC_N * HD_DIM;

  // prologue: stage chunk 0 into buffer 0
#pragma unroll
  for (int r = 0; r < HC_N; r++) {
    f32x4 v = *(const f32x4*)(hs + rowbase + (size_t)r * HD_DIM + tid * 4);
    *(f32x4*)(&lds[0][r][tid * 4]) = v;
  }
  __syncthreads();

  for (int it = 0; it < 16; ++it) {
    const int cur = it & 1;
    // issue next chunk's global loads early (drain across compute phase)
    f32x4 nx[HC_N];
    if (it + 1 < 16) {
#pragma unroll
      for (int r = 0; r < HC_N; r++)
        nx[r] = *(const f32x4*)(hs + rowbase + (size_t)r * HD_DIM + (it + 1) * 1024 + tid * 4);
    }
    // fn prefetch for ii = 0
    f32x4 fvp[6];
#pragma unroll
    for (int j = 0; j < 6; j++)
      fvp[j] = *(const f32x4*)(fn + (size_t)(mbase + j) * HD_DIM + it * 1024 + lane * 4);

#pragma unroll
    for (int ii = 0; ii < 4; ii++) {
      const int c4 = ii * 64 + lane;   // f32x4 index within the 1024-float chunk
      f32x4 h4[HC_N];
#pragma unroll
      for (int r = 0; r < HC_N; r++) h4[r] = *(const f32x4*)(&lds[cur][r][c4 * 4]);
      f32x4 fv[6];
#pragma unroll
      for (int j = 0; j < 6; j++) fv[j] = fvp[j];
      if (ii + 1 < 4) {
#pragma unroll
        for (int j = 0; j < 6; j++)
          fvp[j] = *(const f32x4*)(fn + (size_t)(mbase + j) * HD_DIM + it * 1024 + (c4 + 64) * 4);
      }
      if (wave == 0) {
#pragma unroll
        for (int r = 0; r < HC_N; r++)
          ss[r] += h4[r].x * h4[r].x + h4[r].y * h4[r].y + h4[r].z * h4[r].z + h4[r].w * h4[r].w;
      }
#pragma unroll
      for (int j = 0; j < 6; j++) {
#pragma unroll
        for (int r = 0; r < HC_N; r++)
          acc[r][j] += h4[r].x * fv[j].x + h4[r].y * fv[j].y + h4[r].z * fv[j].z + h4[r].w * fv[j].w;
      }
    }

    if (it + 1 < 16) {
#pragma unroll
      for (int r = 0; r < HC_N; r++)
        *(f32x4*)(&lds[cur ^ 1][r][tid * 4]) = nx[r];
      __syncthreads();
    }
  }

  // per-wave shuffle reduction; each wave owns its 6 m values outright
#pragma unroll
  for (int r = 0; r < HC_N; r++) {
#pragma unroll
    for (int j = 0; j < 6; j++) {
      float v = acc[r][j];
#pragma unroll
      for (int off = 32; off >= 1; off >>= 1) v += __shfl_xor(v, off, 64);
      if (lane == 0) mixraw[(size_t)(b * 4 + r) * MIXN + mbase + j] = v;
    }
  }
  if (wave == 0) {
#pragma unroll
    for (int r = 0; r < HC_N; r++) {
      float v = ss[r];
#pragma unroll
      for (int off = 32; off >= 1; off >>= 1) v += __shfl_xor(v, off, 64);
      if (lane == 0) sumsq[b * 4 + r] = v;
    }
  }
}

// ---------------------------------------------------------------------------
// K2: gates = {pre[4], post[4], sinkhorn(comb)[16]} per row
__global__ __launch_bounds__(256) void k_gates(const float* __restrict__ mixraw,
                                               const float* __restrict__ sumsq,
                                               const float* __restrict__ hbase,
                                               const float* __restrict__ hscale,
                                               float* __restrict__ gates) {
  const int row = blockIdx.x * 256 + threadIdx.x;
  const float rs = rsqrtf(sumsq[row] * (1.0f / HD_DIM) + 1e-6f);
  const float ps = hscale[0], qs = hscale[1], cs = hscale[2];
  const float* mr = mixraw + (size_t)row * MIXN;
  float g[MIXN];
#pragma unroll
  for (int m = 0; m < MIXN; m++) {
    const float sc = (m < 4) ? ps : ((m < 8) ? qs : cs);
    const float x = mr[m] * rs * sc + hbase[m];
    g[m] = 1.0f / (1.0f + expf(-x)) + 1e-6f;
  }
  // 20-iter Sinkhorn on g[8..23] viewed as c[i][j] = g[8+i*4+j]
  for (int t = 0; t < SINK_IT; t++) {
#pragma unroll
    for (int i = 0; i < 4; i++) {
      const float s = g[8 + i * 4 + 0] + g[8 + i * 4 + 1] + g[8 + i * 4 + 2] + g[8 + i * 4 + 3] + 1e-6f;
#pragma unroll
      for (int j = 0; j < 4; j++) g[8 + i * 4 + j] /= s;
    }
#pragma unroll
    for (int j = 0; j < 4; j++) {
      const float s = g[8 + 0 + j] + g[8 + 4 + j] + g[8 + 8 + j] + g[8 + 12 + j] + 1e-6f;
#pragma unroll
      for (int i = 0; i < 4; i++) g[8 + i * 4 + j] /= s;
    }
  }
  float* go = gates + (size_t)row * MIXN;
#pragma unroll
  for (int m = 0; m < MIXN; m++) go[m] = g[m];
}

// ---------------------------------------------------------------------------
// K3: reduced = pre . hs  -> RMSNorm -> normed (bf16).  One block per row s.
__global__ __launch_bounds__(256) void k_reduce_norm(const float* __restrict__ hs,
                                                     const float* __restrict__ gates,
                                                     const float* __restrict__ nw,
                                                     unsigned short* __restrict__ normed) {
  const int s = blockIdx.x, tid = threadIdx.x;
  const int lane = tid & 63, wave = tid >> 6;
  const float* g = gates + (size_t)s * MIXN;
  const float p0 = g[0], p1 = g[1], p2 = g[2], p3 = g[3];
  const size_t base = (size_t)s * HC_N * H_DIM;

  f32x4 red[4];
  float ssq = 0.f;
#pragma unroll
  for (int it = 0; it < 4; ++it) {
    const int d4 = it * 256 + tid;
    f32x4 a = *(const f32x4*)(hs + base + (size_t)0 * H_DIM + (size_t)d4 * 4);
    f32x4 b = *(const f32x4*)(hs + base + (size_t)1 * H_DIM + (size_t)d4 * 4);
    f32x4 c = *(const f32x4*)(hs + base + (size_t)2 * H_DIM + (size_t)d4 * 4);
    f32x4 d = *(const f32x4*)(hs + base + (size_t)3 * H_DIM + (size_t)d4 * 4);
    f32x4 v = p0 * a + p1 * b + p2 * c + p3 * d;
    red[it] = v;
    ssq += v.x * v.x + v.y * v.y + v.z * v.z + v.w * v.w;
  }
#pragma unroll
  for (int off = 32; off >= 1; off >>= 1) ssq += __shfl_xor(ssq, off, 64);
  __shared__ float ls[4];
  if (lane == 0) ls[wave] = ssq;
  __syncthreads();
  const float tot = ls[0] + ls[1] + ls[2] + ls[3];
  const float nr = rsqrtf(tot * (1.0f / H_DIM) + 1e-6f);
#pragma unroll
  for (int it = 0; it < 4; ++it) {
    const int d4 = it * 256 + tid;
    f32x4 w = *(const f32x4*)(nw + (size_t)d4 * 4);
    f32x4 v = red[it] * nr;
    v = v * w;
    u16x4 o;
    o[0] = f2bf(v.x); o[1] = f2bf(v.y); o[2] = f2bf(v.z); o[3] = f2bf(v.w);
    *(u16x4*)(normed + (size_t)s * H_DIM + (size_t)d4 * 4) = o;
  }
}

// ---------------------------------------------------------------------------
// K4: bf16 GEMM  C[s][e] = sum_d A[s][d] * B[e][d]
// ROUND-10: back to the m97-class 128x128 2-barrier single-buffered BK=32
// structure (multi-block/CU: cross-block staging/MFMA overlap, the m114
// mechanism the 1-block 256x256 8-phase cannot have) + the R8-proven
// zero-conflict quad swizzle + __launch_bounds__(256,4) pinning 4 blocks/CU.
// m103 proves 912 TF (~150us here) for this structure on this chip; my R2
// version of it (207us) had 1.68e7 4-way conflicts, now removed.
__device__ __forceinline__ void gload_lds16(const unsigned short* g, unsigned short* l) {
  __builtin_amdgcn_global_load_lds(
      (const __attribute__((address_space(1))) unsigned int*)(const void*)g,
      (__attribute__((address_space(3))) unsigned int*)(void*)l, 16, 0, 0);
}

__global__ __launch_bounds__(256, 4) void k_gemm(const unsigned short* __restrict__ A,
                                                 const unsigned short* __restrict__ B,
                                                 unsigned short* __restrict__ C) {
  __shared__ __align__(16) unsigned short sA[128 * 32];
  __shared__ __align__(16) unsigned short sB[128 * 32];
  const int tid = threadIdx.x;
  const int lane = tid & 63, wave = tid >> 6;
  const int bm = blockIdx.y, bn = blockIdx.x;
  const int wm = wave >> 1, wn = wave & 1;

  f32x4 zero = {0.f, 0.f, 0.f, 0.f};
  f32x4 acc[4][4];
#pragma unroll
  for (int mi = 0; mi < 4; mi++)
#pragma unroll
    for (int ni = 0; ni < 4; ni++) acc[mi][ni] = zero;

  // staging: chunk c (16 rows x 32k) staged by one gload_lds16; lane l ->
  // row c*16 + (l>>2), phys k-chunk (l&3). Pre-swizzled GLOBAL source:
  // logical chunk = (l&3) ^ ((row>>1)&3) = (l&3) ^ ((l>>3)&3).
  const int strow = lane >> 2;          // 0..15
  const int stk = (((lane & 3) ^ ((lane >> 3) & 3)) * 8);  // swizzled src k-off
  const unsigned short* ga = A + (size_t)(bm * 128) * 4096;
  const unsigned short* gb = B + (size_t)(bn * 128) * 4096;
  const int c0 = wave * 2, c1 = wave * 2 + 1;

  // fragment read: row = base16 + (lane&15); logical k-chunk = lane>>4;
  // phys chunk = (lane>>4) ^ ((row>>1)&3) -> uniform 2 lanes/bank = free.
  const int rb = lane & 15;
  const int fk = (((lane >> 4) ^ ((lane >> 1) & 3)) * 8);

  for (int kk = 0; kk < 4096; kk += 32) {
    gload_lds16(ga + (size_t)(c0 * 16 + strow) * 4096 + kk + stk, sA + c0 * 512);
    gload_lds16(ga + (size_t)(c1 * 16 + strow) * 4096 + kk + stk, sA + c1 * 512);
    gload_lds16(gb + (size_t)(c0 * 16 + strow) * 4096 + kk + stk, sB + c0 * 512);
    gload_lds16(gb + (size_t)(c1 * 16 + strow) * 4096 + kk + stk, sB + c1 * 512);
    __syncthreads();

    bf16x8 af[4], bfr[4];
#pragma unroll
    for (int mi = 0; mi < 4; mi++)
      af[mi] = *(const bf16x8*)(sA + (wm * 64 + mi * 16 + rb) * 32 + fk);
#pragma unroll
    for (int ni = 0; ni < 4; ni++)
      bfr[ni] = *(const bf16x8*)(sB + (wn * 64 + ni * 16 + rb) * 32 + fk);
#pragma unroll
    for (int mi = 0; mi < 4; mi++)
#pragma unroll
      for (int ni = 0; ni < 4; ni++)
        acc[mi][ni] = __builtin_amdgcn_mfma_f32_16x16x32_bf16(af[mi], bfr[ni], acc[mi][ni], 0, 0, 0);
    __syncthreads();
  }

  const int cr = (lane >> 4) * 4, cc = lane & 15;
#pragma unroll
  for (int mi = 0; mi < 4; mi++)
#pragma unroll
    for (int ni = 0; ni < 4; ni++)
#pragma unroll
      for (int j = 0; j < 4; j++) {
        const int row = bm * 128 + wm * 64 + mi * 16 + cr + j;
        const int col = bn * 128 + wn * 64 + ni * 16 + cc;
        C[(size_t)row * 4096 + col] = f2bf(acc[mi][ni][j]);
      }
}

// ---------------------------------------------------------------------------
// K5: expanded[s][h][d] = post[h]*out[s][d] + sum_k comb[h][k]*hs[s][k][d]
__global__ __launch_bounds__(256) void k_expand(const float* __restrict__ hs,
                                                const unsigned short* __restrict__ outb,
                                                const float* __restrict__ gates,
                                                float* __restrict__ y) {
  const int s = blockIdx.x, tid = threadIdx.x;
  const float* g = gates + (size_t)s * MIXN;
  float post[4], cb[4][4];
#pragma unroll
  for (int h = 0; h < 4; h++) post[h] = g[4 + h];
#pragma unroll
  for (int h = 0; h < 4; h++)
#pragma unroll
    for (int k = 0; k < 4; k++) cb[h][k] = g[8 + h * 4 + k];

  const size_t base = (size_t)s * HC_N * H_DIM;
#pragma unroll
  for (int it = 0; it < 4; ++it) {
    const int d4 = it * 256 + tid;
    f32x4 hv[4];
#pragma unroll
    for (int k = 0; k < 4; k++)
      hv[k] = *(const f32x4*)(hs + base + (size_t)k * H_DIM + (size_t)d4 * 4);
    u16x4 ob = *(const u16x4*)(outb + (size_t)s * H_DIM + (size_t)d4 * 4);
    f32x4 o = {bf2f(ob[0]), bf2f(ob[1]), bf2f(ob[2]), bf2f(ob[3])};
#pragma unroll
    for (int h = 0; h < 4; h++) {
      f32x4 e = post[h] * o + cb[h][0] * hv[0] + cb[h][1] * hv[1] + cb[h][2] * hv[2] + cb[h][3] * hv[3];
      *(f32x4*)(y + base + (size_t)h * H_DIM + (size_t)d4 * 4) = e;
    }
  }
}

// ---------------------------------------------------------------------------
extern "C" void kernel_launch(void* const* d_in, const int* in_sizes, int n_in,
                              void* d_out, int out_size, void* d_ws, size_t ws_size,
                              hipStream_t stream) {
  const float* hs = (const float*)d_in[0];      // [1,4096,4,4096]
  const float* fn = (const float*)d_in[1];      // [24,16384]
  const float* hbase = (const float*)d_in[2];   // [24]
  const float* hscale = (const float*)d_in[3];  // [3]
  const float* nw = (const float*)d_in[4];      // [4096]
  const float* wi = (const float*)d_in[5];      // [4096,4096]
  float* y = (float*)d_out;                     // [1,4096,4,4096] fp32

  char* ws = (char*)d_ws;
  float* mixraw = (float*)(ws);                            // 4096*24*4   = 393216
  float* sumsq = (float*)(ws + 393216);                    // 4096*4      = 16384
  float* gates = (float*)(ws + 409600);                    // 4096*24*4   = 393216
  unsigned short* normed = (unsigned short*)(ws + 1048576);            // 32MB bf16
  unsigned short* wb = (unsigned short*)(ws + 1048576 + 33554432);     // 32MB bf16
  unsigned short* outb = (unsigned short*)(ws + 1048576 + 2 * 33554432); // 32MB bf16
  // total ws use: ~97MB

  k_w2bf<<<8192, 256, 0, stream>>>(wi, wb);
  k_mixes<<<1024, 256, 0, stream>>>(hs, fn, mixraw, sumsq);
  k_gates<<<16, 256, 0, stream>>>(mixraw, sumsq, hbase, hscale, gates);
  k_reduce_norm<<<4096, 256, 0, stream>>>(hs, gates, nw, normed);
  k_gemm<<<dim3(32, 32), 256, 0, stream>>>(normed, wb, outb);
  k_expand<<<4096, 256, 0, stream>>>(hs, outb, gates, y);
}

// Round 12
// 435.028 us; speedup vs baseline: 1.1650x; 1.0521x over previous
//
#include <hip/hip_runtime.h>
#include <math.h>

// Problem dims (fixed by the reference)
#define S_DIM 4096
#define H_DIM 4096
#define HC_N 4
#define HD_DIM 16384   // HC_N * H_DIM
#define MIXN 24        // (2+HC)*HC
#define SINK_IT 20
#define KSPL 32        // K-split for mixgemm (512 k per slice)

typedef float f32x4 __attribute__((ext_vector_type(4)));
typedef __bf16 bf16x8 __attribute__((ext_vector_type(8)));
typedef unsigned short u16x8 __attribute__((ext_vector_type(8)));
typedef unsigned short u16x4 __attribute__((ext_vector_type(4)));

__device__ __forceinline__ unsigned short f2bf(float f) {
  unsigned u = __builtin_bit_cast(unsigned, f);
  u += 0x7FFFu + ((u >> 16) & 1u);   // round-to-nearest-even
  return (unsigned short)(u >> 16);
}
__device__ __forceinline__ float bf2f(unsigned short h) {
  return __builtin_bit_cast(float, (unsigned)h << 16);
}

// ---------------------------------------------------------------------------
// K0: fp32->bf16 conversions: w_inner (blocks 0..8191), hc_fn (8192..8383),
// fnb zero-pad rows 24..31 (8384..8447).
__global__ __launch_bounds__(256) void k_w2bf(const float* __restrict__ w,
                                              unsigned short* __restrict__ wb,
                                              const float* __restrict__ fn,
                                              unsigned short* __restrict__ fnb) {
  const int b = blockIdx.x;
  if (b < 8192) {
    const size_t i = (size_t)b * 2048 + threadIdx.x * 8;
    f32x4 a = *(const f32x4*)(w + i);
    f32x4 c = *(const f32x4*)(w + i + 4);
    u16x8 o;
    o[0] = f2bf(a.x); o[1] = f2bf(a.y); o[2] = f2bf(a.z); o[3] = f2bf(a.w);
    o[4] = f2bf(c.x); o[5] = f2bf(c.y); o[6] = f2bf(c.z); o[7] = f2bf(c.w);
    *(u16x8*)(wb + i) = o;
  } else if (b < 8384) {
    const size_t i = (size_t)(b - 8192) * 2048 + threadIdx.x * 8;  // < 393216
    f32x4 a = *(const f32x4*)(fn + i);
    f32x4 c = *(const f32x4*)(fn + i + 4);
    u16x8 o;
    o[0] = f2bf(a.x); o[1] = f2bf(a.y); o[2] = f2bf(a.z); o[3] = f2bf(a.w);
    o[4] = f2bf(c.x); o[5] = f2bf(c.y); o[6] = f2bf(c.z); o[7] = f2bf(c.w);
    *(u16x8*)(fnb + i) = o;
  } else {
    const size_t i = 393216 + (size_t)(b - 8384) * 2048 + threadIdx.x * 8;
    u16x8 o = {0, 0, 0, 0, 0, 0, 0, 0};
    *(u16x8*)(fnb + i) = o;
  }
}

// ---------------------------------------------------------------------------
// K1: mixes as MFMA GEMM: mixpart[row][p][24] += hs[row,:] . fnb[m,:] over
// the p-th K-slice (512 k). hs read fp32 directly from global (each element
// exactly once chip-wide), converted in-register to bf16; fp32 sumsq from
// the SAME loads pre-conversion -> sumsqpart[row][p]. 1024 blocks (4/CU).
// Fragment + C layouts mirror the refcheck-passing k_gemm. Deterministic
// (K-split partials, no atomics); k_gates sums the 32 partials.
__global__ __launch_bounds__(256) void k_mixgemm(const float* __restrict__ hs,
                                                 const unsigned short* __restrict__ fnb,
                                                 float* __restrict__ mixpart,
                                                 float* __restrict__ sumsqpart) {
  const int rt = blockIdx.x;    // row tile: 128 rows
  const int p = blockIdx.y;     // k slice: 512 k
  const int tid = threadIdx.x, lane = tid & 63, wave = tid >> 6;
  const int r16 = lane & 15, kq = lane >> 4;
  const int row0 = rt * 128 + wave * 32;
  const size_t kbase = (size_t)p * 512 + kq * 8;

  f32x4 acc[2][2];
  f32x4 zero = {0.f, 0.f, 0.f, 0.f};
  acc[0][0] = zero; acc[0][1] = zero; acc[1][0] = zero; acc[1][1] = zero;
  float ss0 = 0.f, ss1 = 0.f;

  const float* a0 = hs + (size_t)(row0 + r16) * HD_DIM + kbase;
  const float* a1 = hs + (size_t)(row0 + 16 + r16) * HD_DIM + kbase;
  const unsigned short* b0p = fnb + (size_t)r16 * HD_DIM + kbase;
  const unsigned short* b1p = fnb + (size_t)(16 + r16) * HD_DIM + kbase;

#pragma unroll 4
  for (int kk = 0; kk < 512; kk += 32) {
    const f32x4 va0 = *(const f32x4*)(a0 + kk);
    const f32x4 va0b = *(const f32x4*)(a0 + kk + 4);
    const f32x4 va1 = *(const f32x4*)(a1 + kk);
    const f32x4 va1b = *(const f32x4*)(a1 + kk + 4);
    const bf16x8 fb0 = *(const bf16x8*)(b0p + kk);
    const bf16x8 fb1 = *(const bf16x8*)(b1p + kk);
    ss0 += va0.x * va0.x + va0.y * va0.y + va0.z * va0.z + va0.w * va0.w
         + va0b.x * va0b.x + va0b.y * va0b.y + va0b.z * va0b.z + va0b.w * va0b.w;
    ss1 += va1.x * va1.x + va1.y * va1.y + va1.z * va1.z + va1.w * va1.w
         + va1b.x * va1b.x + va1b.y * va1b.y + va1b.z * va1b.z + va1b.w * va1b.w;
    bf16x8 fa0, fa1;
    fa0[0] = (__bf16)va0.x; fa0[1] = (__bf16)va0.y; fa0[2] = (__bf16)va0.z; fa0[3] = (__bf16)va0.w;
    fa0[4] = (__bf16)va0b.x; fa0[5] = (__bf16)va0b.y; fa0[6] = (__bf16)va0b.z; fa0[7] = (__bf16)va0b.w;
    fa1[0] = (__bf16)va1.x; fa1[1] = (__bf16)va1.y; fa1[2] = (__bf16)va1.z; fa1[3] = (__bf16)va1.w;
    fa1[4] = (__bf16)va1b.x; fa1[5] = (__bf16)va1b.y; fa1[6] = (__bf16)va1b.z; fa1[7] = (__bf16)va1b.w;
    acc[0][0] = __builtin_amdgcn_mfma_f32_16x16x32_bf16(fa0, fb0, acc[0][0], 0, 0, 0);
    acc[0][1] = __builtin_amdgcn_mfma_f32_16x16x32_bf16(fa0, fb1, acc[0][1], 0, 0, 0);
    acc[1][0] = __builtin_amdgcn_mfma_f32_16x16x32_bf16(fa1, fb0, acc[1][0], 0, 0, 0);
    acc[1][1] = __builtin_amdgcn_mfma_f32_16x16x32_bf16(fa1, fb1, acc[1][1], 0, 0, 0);
  }

  // sumsq: combine lanes sharing (lane&15) -> rows row0+r16, row0+16+r16
  ss0 += __shfl_xor(ss0, 16, 64); ss0 += __shfl_xor(ss0, 32, 64);
  ss1 += __shfl_xor(ss1, 16, 64); ss1 += __shfl_xor(ss1, 32, 64);
  if (lane < 16) {
    sumsqpart[(size_t)(row0 + lane) * KSPL + p] = ss0;
    sumsqpart[(size_t)(row0 + 16 + lane) * KSPL + p] = ss1;
  }

  // C write: row = row0 + mi*16 + (lane>>4)*4 + j, col = ni*16 + (lane&15)
  const int cr = (lane >> 4) * 4, cc = lane & 15;
#pragma unroll
  for (int mi = 0; mi < 2; mi++)
#pragma unroll
    for (int ni = 0; ni < 2; ni++) {
      const int col = ni * 16 + cc;
      if (col < MIXN) {
#pragma unroll
        for (int j = 0; j < 4; j++) {
          const int row = row0 + mi * 16 + cr + j;
          mixpart[((size_t)row * KSPL + p) * MIXN + col] = acc[mi][ni][j];
        }
      }
    }
}

// ---------------------------------------------------------------------------
// K2: gates: sum the K-split partials, sigmoid + 20-iter Sinkhorn per row
__global__ __launch_bounds__(256) void k_gates(const float* __restrict__ mixpart,
                                               const float* __restrict__ sumsqpart,
                                               const float* __restrict__ hbase,
                                               const float* __restrict__ hscale,
                                               float* __restrict__ gates) {
  const int row = blockIdx.x * 256 + threadIdx.x;
  float sumsq = 0.f;
  const float* sp = sumsqpart + (size_t)row * KSPL;
#pragma unroll
  for (int p = 0; p < KSPL; p++) sumsq += sp[p];
  float mr[MIXN];
#pragma unroll
  for (int m = 0; m < MIXN; m++) mr[m] = 0.f;
  const float* mp = mixpart + (size_t)row * KSPL * MIXN;
  for (int p = 0; p < KSPL; p++) {
#pragma unroll
    for (int m = 0; m < MIXN; m++) mr[m] += mp[p * MIXN + m];
  }
  const float rs = rsqrtf(sumsq * (1.0f / HD_DIM) + 1e-6f);
  const float ps = hscale[0], qs = hscale[1], cs = hscale[2];
  float g[MIXN];
#pragma unroll
  for (int m = 0; m < MIXN; m++) {
    const float sc = (m < 4) ? ps : ((m < 8) ? qs : cs);
    const float x = mr[m] * rs * sc + hbase[m];
    g[m] = 1.0f / (1.0f + expf(-x)) + 1e-6f;
  }
  for (int t = 0; t < SINK_IT; t++) {
#pragma unroll
    for (int i = 0; i < 4; i++) {
      const float s = g[8 + i * 4 + 0] + g[8 + i * 4 + 1] + g[8 + i * 4 + 2] + g[8 + i * 4 + 3] + 1e-6f;
#pragma unroll
      for (int j = 0; j < 4; j++) g[8 + i * 4 + j] /= s;
    }
#pragma unroll
    for (int j = 0; j < 4; j++) {
      const float s = g[8 + 0 + j] + g[8 + 4 + j] + g[8 + 8 + j] + g[8 + 12 + j] + 1e-6f;
#pragma unroll
      for (int i = 0; i < 4; i++) g[8 + i * 4 + j] /= s;
    }
  }
  float* go = gates + (size_t)row * MIXN;
#pragma unroll
  for (int m = 0; m < MIXN; m++) go[m] = g[m];
}

// ---------------------------------------------------------------------------
// K3: reduced = pre . hs  -> RMSNorm -> normed (bf16).  One block per row s.
__global__ __launch_bounds__(256) void k_reduce_norm(const float* __restrict__ hs,
                                                     const float* __restrict__ gates,
                                                     const float* __restrict__ nw,
                                                     unsigned short* __restrict__ normed) {
  const int s = blockIdx.x, tid = threadIdx.x;
  const int lane = tid & 63, wave = tid >> 6;
  const float* g = gates + (size_t)s * MIXN;
  const float p0 = g[0], p1 = g[1], p2 = g[2], p3 = g[3];
  const size_t base = (size_t)s * HC_N * H_DIM;

  f32x4 red[4];
  float ssq = 0.f;
#pragma unroll
  for (int it = 0; it < 4; ++it) {
    const int d4 = it * 256 + tid;
    f32x4 a = *(const f32x4*)(hs + base + (size_t)0 * H_DIM + (size_t)d4 * 4);
    f32x4 b = *(const f32x4*)(hs + base + (size_t)1 * H_DIM + (size_t)d4 * 4);
    f32x4 c = *(const f32x4*)(hs + base + (size_t)2 * H_DIM + (size_t)d4 * 4);
    f32x4 d = *(const f32x4*)(hs + base + (size_t)3 * H_DIM + (size_t)d4 * 4);
    f32x4 v = p0 * a + p1 * b + p2 * c + p3 * d;
    red[it] = v;
    ssq += v.x * v.x + v.y * v.y + v.z * v.z + v.w * v.w;
  }
#pragma unroll
  for (int off = 32; off >= 1; off >>= 1) ssq += __shfl_xor(ssq, off, 64);
  __shared__ float ls[4];
  if (lane == 0) ls[wave] = ssq;
  __syncthreads();
  const float tot = ls[0] + ls[1] + ls[2] + ls[3];
  const float nr = rsqrtf(tot * (1.0f / H_DIM) + 1e-6f);
#pragma unroll
  for (int it = 0; it < 4; ++it) {
    const int d4 = it * 256 + tid;
    f32x4 w = *(const f32x4*)(nw + (size_t)d4 * 4);
    f32x4 v = red[it] * nr;
    v = v * w;
    u16x4 o;
    o[0] = f2bf(v.x); o[1] = f2bf(v.y); o[2] = f2bf(v.z); o[3] = f2bf(v.w);
    *(u16x4*)(normed + (size_t)s * H_DIM + (size_t)d4 * 4) = o;
  }
}

// ---------------------------------------------------------------------------
// K4: bf16 GEMM  C[s][e] = sum_d A[s][d] * B[e][d]
// FROZEN (R11 win): m97-class 128x128 2-barrier single-buffered BK=32,
// multi-block/CU (4 pinned), zero-conflict quad swizzle. 172us, 797 TF.
__device__ __forceinline__ void gload_lds16(const unsigned short* g, unsigned short* l) {
  __builtin_amdgcn_global_load_lds(
      (const __attribute__((address_space(1))) unsigned int*)(const void*)g,
      (__attribute__((address_space(3))) unsigned int*)(void*)l, 16, 0, 0);
}

__global__ __launch_bounds__(256, 4) void k_gemm(const unsigned short* __restrict__ A,
                                                 const unsigned short* __restrict__ B,
                                                 unsigned short* __restrict__ C) {
  __shared__ __align__(16) unsigned short sA[128 * 32];
  __shared__ __align__(16) unsigned short sB[128 * 32];
  const int tid = threadIdx.x;
  const int lane = tid & 63, wave = tid >> 6;
  const int bm = blockIdx.y, bn = blockIdx.x;
  const int wm = wave >> 1, wn = wave & 1;

  f32x4 zero = {0.f, 0.f, 0.f, 0.f};
  f32x4 acc[4][4];
#pragma unroll
  for (int mi = 0; mi < 4; mi++)
#pragma unroll
    for (int ni = 0; ni < 4; ni++) acc[mi][ni] = zero;

  const int strow = lane >> 2;          // 0..15
  const int stk = (((lane & 3) ^ ((lane >> 3) & 3)) * 8);  // swizzled src k-off
  const unsigned short* ga = A + (size_t)(bm * 128) * 4096;
  const unsigned short* gb = B + (size_t)(bn * 128) * 4096;
  const int c0 = wave * 2, c1 = wave * 2 + 1;

  const int rb = lane & 15;
  const int fk = (((lane >> 4) ^ ((lane >> 1) & 3)) * 8);

  for (int kk = 0; kk < 4096; kk += 32) {
    gload_lds16(ga + (size_t)(c0 * 16 + strow) * 4096 + kk + stk, sA + c0 * 512);
    gload_lds16(ga + (size_t)(c1 * 16 + strow) * 4096 + kk + stk, sA + c1 * 512);
    gload_lds16(gb + (size_t)(c0 * 16 + strow) * 4096 + kk + stk, sB + c0 * 512);
    gload_lds16(gb + (size_t)(c1 * 16 + strow) * 4096 + kk + stk, sB + c1 * 512);
    __syncthreads();

    bf16x8 af[4], bfr[4];
#pragma unroll
    for (int mi = 0; mi < 4; mi++)
      af[mi] = *(const bf16x8*)(sA + (wm * 64 + mi * 16 + rb) * 32 + fk);
#pragma unroll
    for (int ni = 0; ni < 4; ni++)
      bfr[ni] = *(const bf16x8*)(sB + (wn * 64 + ni * 16 + rb) * 32 + fk);
#pragma unroll
    for (int mi = 0; mi < 4; mi++)
#pragma unroll
      for (int ni = 0; ni < 4; ni++)
        acc[mi][ni] = __builtin_amdgcn_mfma_f32_16x16x32_bf16(af[mi], bfr[ni], acc[mi][ni], 0, 0, 0);
    __syncthreads();
  }

  const int cr = (lane >> 4) * 4, cc = lane & 15;
#pragma unroll
  for (int mi = 0; mi < 4; mi++)
#pragma unroll
    for (int ni = 0; ni < 4; ni++)
#pragma unroll
      for (int j = 0; j < 4; j++) {
        const int row = bm * 128 + wm * 64 + mi * 16 + cr + j;
        const int col = bn * 128 + wn * 64 + ni * 16 + cc;
        C[(size_t)row * 4096 + col] = f2bf(acc[mi][ni][j]);
      }
}

// ---------------------------------------------------------------------------
// K5: expanded[s][h][d] = post[h]*out[s][d] + sum_k comb[h][k]*hs[s][k][d]
__global__ __launch_bounds__(256) void k_expand(const float* __restrict__ hs,
                                                const unsigned short* __restrict__ outb,
                                                const float* __restrict__ gates,
                                                float* __restrict__ y) {
  const int s = blockIdx.x, tid = threadIdx.x;
  const float* g = gates + (size_t)s * MIXN;
  float post[4], cb[4][4];
#pragma unroll
  for (int h = 0; h < 4; h++) post[h] = g[4 + h];
#pragma unroll
  for (int h = 0; h < 4; h++)
#pragma unroll
    for (int k = 0; k < 4; k++) cb[h][k] = g[8 + h * 4 + k];

  const size_t base = (size_t)s * HC_N * H_DIM;
#pragma unroll
  for (int it = 0; it < 4; ++it) {
    const int d4 = it * 256 + tid;
    f32x4 hv[4];
#pragma unroll
    for (int k = 0; k < 4; k++)
      hv[k] = *(const f32x4*)(hs + base + (size_t)k * H_DIM + (size_t)d4 * 4);
    u16x4 ob = *(const u16x4*)(outb + (size_t)s * H_DIM + (size_t)d4 * 4);
    f32x4 o = {bf2f(ob[0]), bf2f(ob[1]), bf2f(ob[2]), bf2f(ob[3])};
#pragma unroll
    for (int h = 0; h < 4; h++) {
      f32x4 e = post[h] * o + cb[h][0] * hv[0] + cb[h][1] * hv[1] + cb[h][2] * hv[2] + cb[h][3] * hv[3];
      *(f32x4*)(y + base + (size_t)h * H_DIM + (size_t)d4 * 4) = e;
    }
  }
}

// ---------------------------------------------------------------------------
extern "C" void kernel_launch(void* const* d_in, const int* in_sizes, int n_in,
                              void* d_out, int out_size, void* d_ws, size_t ws_size,
                              hipStream_t stream) {
  const float* hs = (const float*)d_in[0];      // [1,4096,4,4096]
  const float* fn = (const float*)d_in[1];      // [24,16384]
  const float* hbase = (const float*)d_in[2];   // [24]
  const float* hscale = (const float*)d_in[3];  // [3]
  const float* nw = (const float*)d_in[4];      // [4096]
  const float* wi = (const float*)d_in[5];      // [4096,4096]
  float* y = (float*)d_out;                     // [1,4096,4,4096] fp32

  char* ws = (char*)d_ws;
  float* gates = (float*)(ws);                                  // 393216 B
  float* sumsqpart = (float*)(ws + 524288);                     // 4096*32*4 = 524288
  float* mixpart = (float*)(ws + 1048576);                      // 4096*32*24*4 = 12.6MB
  unsigned short* fnb = (unsigned short*)(ws + 13631488);       // 32*16384*2 = 1MB
  unsigned short* normed = (unsigned short*)(ws + 16777216);    // 32MB bf16
  unsigned short* wb = (unsigned short*)(ws + 50331648);        // 32MB bf16
  unsigned short* outb = (unsigned short*)(ws + 83886080);      // 32MB bf16
  // total ws use: ~112MB

  k_w2bf<<<8448, 256, 0, stream>>>(wi, wb, fn, fnb);
  k_mixgemm<<<dim3(32, 32), 256, 0, stream>>>(hs, fnb, mixpart, sumsqpart);
  k_gates<<<16, 256, 0, stream>>>(mixpart, sumsqpart, hbase, hscale, gates);
  k_reduce_norm<<<4096, 256, 0, stream>>>(hs, gates, nw, normed);
  k_gemm<<<dim3(32, 32), 256, 0, stream>>>(normed, wb, outb);
  k_expand<<<4096, 256, 0, stream>>>(hs, outb, gates, y);
}